// Round 2
// baseline (304.310 us; speedup 1.0000x reference)
//
#include <hip/hip_runtime.h>

// VQ-VAE vector quantization, MI355X gfx950.
// B=16, C=64, H=W=64 -> N=65536 pixels; K=1024 codes, dim 64.
// NUMERICS (DO NOT CHANGE — r7 passed absmax 0.0 with exactly this):
//   nz/ne: numpy pairwise sum, 8-accumulator unroll, products rounded
//          separately (no fma contraction);
//   dot:   single ascending fp32 fma chain per (pixel,code);
//   d = fl( fl(nz - fl(2*dot)) + ne ); strict-< ascending-k tie-break.
//   ~135 pixels are decided by quantized ties.
//
// Perf history: r7 LDS-broadcast PXT=1 161 µs; r8 uniform global loads 185 µs;
// r9 PXT=2 + launch_bounds(256,2) 137 µs argmin / 197 total (VALUBusy 65%,
// occ 20%, VGPR 88 arch + ~160 acc = 248 at the 256/wave cap, LDS conf 0).
// r10 PXT=3@(256,2) never ran (infra) — and would have spilled: 240+ regs
// needed vs 256 cap. r11 analysis: VALU-issue time 89 µs vs 60 µs FMA floor
// suggests AGPR-resident zr + 8:1 FMA:ds_read contention. Fix both with
// PXT=4 @ launch_bounds(256,1): 512-reg budget (256 arch + acc), 16:1
// FMA:LDS, 1 wave/SIMD (8 indep FMA chains cover the 4-cyc dep latency),
// grid 64x8 = 512 blocks = exactly 2 clean rounds, no tail guards.
// Fused: prep into argmin (sn from bit-exact LDS copy, loop lexically under
// contract(off) — textually identical to verified vq_prep); loss scale/emit
// into finalize via done-counter (4 -> 2 dispatches).
#define N_PIX   65536
#define CDIM    64
#define KCODES  1024
#define HWSZ    4096          // H*W
#define KCHUNK  128           // codes per argmin block
#define NCHUNK  8             // KCODES / KCHUNK
#define TPB     256
#define PXT     4             // pixels per thread; 64*256*4 == N_PIX exactly
#define GRIDX   (N_PIX / (TPB * PXT))   // 64

// workspace layout (float-element offsets)
#define OFF_CTR  0            // 1 u32: finalize done-counter
#define OFF_MIN  1024         // 65536*8 f32: per-chunk min score
#define OFF_IDX  525312       // 65536*8 i32: per-chunk argmin
#define OFF_LOSS 1049600      // 1 f32: SSE accumulator

// output layout (float-element offsets): z_q | indices | loss
#define OUT_IDX  (N_PIX * CDIM)         // 4194304
#define OUT_LOSS (OUT_IDX + N_PIX)      // 4259840

// exact numpy pairwise ||.||^2 for pixel registers — EXACT r9-verified form.
__device__ __forceinline__ float np_nz(const float* zr) {
    float r0 = zr[0]*zr[0], r1 = zr[1]*zr[1], r2 = zr[2]*zr[2], r3 = zr[3]*zr[3];
    float r4 = zr[4]*zr[4], r5 = zr[5]*zr[5], r6 = zr[6]*zr[6], r7 = zr[7]*zr[7];
#pragma unroll
    for (int i = 8; i < CDIM; i += 8) {
        r0 = r0 + zr[i+0]*zr[i+0]; r1 = r1 + zr[i+1]*zr[i+1];
        r2 = r2 + zr[i+2]*zr[i+2]; r3 = r3 + zr[i+3]*zr[i+3];
        r4 = r4 + zr[i+4]*zr[i+4]; r5 = r5 + zr[i+5]*zr[i+5];
        r6 = r6 + zr[i+6]*zr[i+6]; r7 = r7 + zr[i+7]*zr[i+7];
    }
    return ((r0 + r1) + (r2 + r3)) + ((r4 + r5) + (r6 + r7));
}

// ---------------- Kernel A: split-K argmin, 4 px/thread, LDS broadcast ------
// grid = (GRIDX, NCHUNK); block = TPB. Also computes ||e||^2 per chunk
// (fused prep) and zeroes the loss slot + done counter.
__global__ __launch_bounds__(TPB, 1) void vq_argmin(const float* __restrict__ z,
                                                    const float* __restrict__ emb,
                                                    float* __restrict__ cmin,
                                                    int* __restrict__ cidx,
                                                    float* __restrict__ ws) {
#pragma clang fp contract(off)
    __shared__ float se[KCHUNK * CDIM];   // 32 KB
    __shared__ float sn[KCHUNK];

    const int chunk = blockIdx.y;
    const int k0 = chunk * KCHUNK;

    if ((blockIdx.x | blockIdx.y) == 0 && threadIdx.x == 0) {
        ws[OFF_LOSS] = 0.0f;                       // stream-ordered before finalize
        ((unsigned*)ws)[OFF_CTR] = 0u;             // graph-replay / re-poison safe
    }

    // stage this chunk's embedding rows (coalesced float4)
    const float4* esrc = (const float4*)(emb + (size_t)k0 * CDIM);
    float4* edst = (float4*)se;
    for (int i = threadIdx.x; i < KCHUNK * CDIM / 4; i += TPB) edst[i] = esrc[i];
    __syncthreads();
    // fused prep: ||e_k||^2 from the bit-exact staged copy. This loop is
    // lexically inside the contract(off) scope and textually identical to the
    // r9-verified vq_prep arithmetic (8-acc pairwise, separate rounding).
    if (threadIdx.x < KCHUNK) {
        const float* e = se + threadIdx.x * CDIM;
        float r0 = e[0]*e[0], r1 = e[1]*e[1], r2 = e[2]*e[2], r3 = e[3]*e[3];
        float r4 = e[4]*e[4], r5 = e[5]*e[5], r6 = e[6]*e[6], r7 = e[7]*e[7];
#pragma unroll
        for (int i = 8; i < CDIM; i += 8) {
            r0 = r0 + e[i+0]*e[i+0]; r1 = r1 + e[i+1]*e[i+1];
            r2 = r2 + e[i+2]*e[i+2]; r3 = r3 + e[i+3]*e[i+3];
            r4 = r4 + e[i+4]*e[i+4]; r5 = r5 + e[i+5]*e[i+5];
            r6 = r6 + e[i+6]*e[i+6]; r7 = r7 + e[i+7]*e[i+7];
        }
        sn[threadIdx.x] = ((r0 + r1) + (r2 + r3)) + ((r4 + r5) + (r6 + r7));
    }
    __syncthreads();

    // four pixels per thread, all lane-coalesced; no tail (64*256*4 == N_PIX)
    const int p0 = blockIdx.x * (TPB * PXT) + threadIdx.x;
    const int p1 = p0 + TPB;
    const int p2 = p1 + TPB;
    const int p3 = p2 + TPB;

    float zr0[CDIM], zr1[CDIM], zr2[CDIM], zr3[CDIM];
    {
        const int b0 = p0 >> 12, hw0 = p0 & (HWSZ - 1);
        const int b1 = p1 >> 12, hw1 = p1 & (HWSZ - 1);
        const int b2 = p2 >> 12, hw2 = p2 & (HWSZ - 1);
        const int b3 = p3 >> 12, hw3 = p3 & (HWSZ - 1);
        const float* zp0 = z + ((size_t)(b0 * CDIM) << 12) + hw0;
        const float* zp1 = z + ((size_t)(b1 * CDIM) << 12) + hw1;
        const float* zp2 = z + ((size_t)(b2 * CDIM) << 12) + hw2;
        const float* zp3 = z + ((size_t)(b3 * CDIM) << 12) + hw3;
#pragma unroll
        for (int c = 0; c < CDIM; ++c) {
            zr0[c] = zp0[(size_t)c << 12];
            zr1[c] = zp1[(size_t)c << 12];
            zr2[c] = zp2[(size_t)c << 12];
            zr3[c] = zp3[(size_t)c << 12];
        }
    }
    const float nz0 = np_nz(zr0);
    const float nz1 = np_nz(zr1);
    const float nz2 = np_nz(zr2);
    const float nz3 = np_nz(zr3);

    float best0 = 3.4e38f, best1 = 3.4e38f, best2 = 3.4e38f, best3 = 3.4e38f;
    int   bi0   = k0,      bi1   = k0,      bi2   = k0,      bi3   = k0;
    for (int kk = 0; kk < KCHUNK; kk += 2) {
        const float4* e0 = (const float4*)(se + kk * CDIM);
        const float4* e1 = e0 + (CDIM / 4);
        float a00 = 0.f, a01 = 0.f, a10 = 0.f, a11 = 0.f;
        float a20 = 0.f, a21 = 0.f, a30 = 0.f, a31 = 0.f;
#pragma unroll
        for (int j = 0; j < 16; ++j) {
            float4 v0 = e0[j];                 // uniform addr -> LDS broadcast
            float4 v1 = e1[j];
            a00 = fmaf(zr0[4*j+0], v0.x, a00);
            a00 = fmaf(zr0[4*j+1], v0.y, a00);
            a00 = fmaf(zr0[4*j+2], v0.z, a00);
            a00 = fmaf(zr0[4*j+3], v0.w, a00);
            a01 = fmaf(zr0[4*j+0], v1.x, a01);
            a01 = fmaf(zr0[4*j+1], v1.y, a01);
            a01 = fmaf(zr0[4*j+2], v1.z, a01);
            a01 = fmaf(zr0[4*j+3], v1.w, a01);
            a10 = fmaf(zr1[4*j+0], v0.x, a10);
            a10 = fmaf(zr1[4*j+1], v0.y, a10);
            a10 = fmaf(zr1[4*j+2], v0.z, a10);
            a10 = fmaf(zr1[4*j+3], v0.w, a10);
            a11 = fmaf(zr1[4*j+0], v1.x, a11);
            a11 = fmaf(zr1[4*j+1], v1.y, a11);
            a11 = fmaf(zr1[4*j+2], v1.z, a11);
            a11 = fmaf(zr1[4*j+3], v1.w, a11);
            a20 = fmaf(zr2[4*j+0], v0.x, a20);
            a20 = fmaf(zr2[4*j+1], v0.y, a20);
            a20 = fmaf(zr2[4*j+2], v0.z, a20);
            a20 = fmaf(zr2[4*j+3], v0.w, a20);
            a21 = fmaf(zr2[4*j+0], v1.x, a21);
            a21 = fmaf(zr2[4*j+1], v1.y, a21);
            a21 = fmaf(zr2[4*j+2], v1.z, a21);
            a21 = fmaf(zr2[4*j+3], v1.w, a21);
            a30 = fmaf(zr3[4*j+0], v0.x, a30);
            a30 = fmaf(zr3[4*j+1], v0.y, a30);
            a30 = fmaf(zr3[4*j+2], v0.z, a30);
            a30 = fmaf(zr3[4*j+3], v0.w, a30);
            a31 = fmaf(zr3[4*j+0], v1.x, a31);
            a31 = fmaf(zr3[4*j+1], v1.y, a31);
            a31 = fmaf(zr3[4*j+2], v1.z, a31);
            a31 = fmaf(zr3[4*j+3], v1.w, a31);
        }
        float d00 = (nz0 - 2.0f * a00) + sn[kk];
        float d01 = (nz0 - 2.0f * a01) + sn[kk + 1];
        float d10 = (nz1 - 2.0f * a10) + sn[kk];
        float d11 = (nz1 - 2.0f * a11) + sn[kk + 1];
        float d20 = (nz2 - 2.0f * a20) + sn[kk];
        float d21 = (nz2 - 2.0f * a21) + sn[kk + 1];
        float d30 = (nz3 - 2.0f * a30) + sn[kk];
        float d31 = (nz3 - 2.0f * a31) + sn[kk + 1];
        if (d00 < best0) { best0 = d00; bi0 = k0 + kk; }
        if (d01 < best0) { best0 = d01; bi0 = k0 + kk + 1; }
        if (d10 < best1) { best1 = d10; bi1 = k0 + kk; }
        if (d11 < best1) { best1 = d11; bi1 = k0 + kk + 1; }
        if (d20 < best2) { best2 = d20; bi2 = k0 + kk; }
        if (d21 < best2) { best2 = d21; bi2 = k0 + kk + 1; }
        if (d30 < best3) { best3 = d30; bi3 = k0 + kk; }
        if (d31 < best3) { best3 = d31; bi3 = k0 + kk + 1; }
    }
    cmin[(p0 << 3) + chunk] = best0;
    cidx[(p0 << 3) + chunk] = bi0;
    cmin[(p1 << 3) + chunk] = best1;
    cidx[(p1 << 3) + chunk] = bi1;
    cmin[(p2 << 3) + chunk] = best2;
    cidx[(p2 << 3) + chunk] = bi2;
    cmin[(p3 << 3) + chunk] = best3;
    cidx[(p3 << 3) + chunk] = bi3;
}

// ---------------- Kernel B: reduce chunks, gather z_q, loss + emit ----------
__global__ __launch_bounds__(TPB) void vq_finalize(const float* __restrict__ z,
                                                   const float* __restrict__ emb,
                                                   const float* __restrict__ cmin,
                                                   const int* __restrict__ cidx,
                                                   float* __restrict__ out,
                                                   float* __restrict__ ws) {
    const int p = blockIdx.x * TPB + threadIdx.x;

    // ascending-chunk strict < keeps the earliest (lowest-k) minimum
    float best = cmin[p << 3];
    int   bi   = cidx[p << 3];
#pragma unroll
    for (int ch = 1; ch < NCHUNK; ++ch) {
        float m = cmin[(p << 3) + ch];
        if (m < best) { best = m; bi = cidx[(p << 3) + ch]; }
    }

    out[OUT_IDX + p] = (float)bi;       // indices output (fp32)

    const float* ev = emb + bi * CDIM;
    const int b  = p >> 12;
    const int hw = p & (HWSZ - 1);
    const float* zp = z + ((size_t)(b * CDIM) << 12) + hw;
    float* zq = out + ((size_t)(b * CDIM) << 12) + hw;

    float ls = 0.0f;
#pragma unroll
    for (int c = 0; c < CDIM; ++c) {
        float e = ev[c];                    // gather: rows hit L1/L2 (256KB table)
        float zv = zp[(size_t)c << 12];
        float d = e - zv;
        ls = fmaf(d, d, ls);
        zq[(size_t)c << 12] = e;            // fp32 z_q, coalesced strided store
    }

    // block reduction -> one atomic per block; last block scales + emits loss
#pragma unroll
    for (int off = 32; off > 0; off >>= 1) ls += __shfl_down(ls, off);
    __shared__ float wsum[TPB / 64];
    if ((threadIdx.x & 63) == 0) wsum[threadIdx.x >> 6] = ls;
    __syncthreads();
    if (threadIdx.x == 0) {
        float s = wsum[0] + wsum[1] + wsum[2] + wsum[3];
        float* loss_acc = ws + OFF_LOSS;
        atomicAdd(loss_acc, s);
        __threadfence();                               // add visible before count
        unsigned* ctr = (unsigned*)ws + OFF_CTR;
        unsigned old = atomicAdd(ctr, 1u);
        if (old == (unsigned)(gridDim.x - 1)) {        // last block: all adds done
            __threadfence();
            float total = atomicAdd(loss_acc, 0.0f);   // coherent L2 read
            // vq_loss + beta*commitment = (1+0.25) * SSE / numel(z)
            out[OUT_LOSS] = total * (1.25f / (float)(N_PIX * CDIM));
        }
    }
}

extern "C" void kernel_launch(void* const* d_in, const int* in_sizes, int n_in,
                              void* d_out, int out_size, void* d_ws, size_t ws_size,
                              hipStream_t stream) {
    const float* z   = (const float*)d_in[0];
    const float* emb = (const float*)d_in[1];
    float* ws   = (float*)d_ws;
    float* out  = (float*)d_out;
    float* cmin = ws + OFF_MIN;
    int*   cidx = (int*)(ws + OFF_IDX);

    vq_argmin<<<dim3(GRIDX, NCHUNK), dim3(TPB), 0, stream>>>(z, emb, cmin, cidx, ws);
    vq_finalize<<<dim3(N_PIX / TPB), dim3(TPB), 0, stream>>>(z, emb, cmin, cidx, out, ws);
}

// Round 3
// 200.192 us; speedup vs baseline: 1.5201x; 1.5201x over previous
//
#include <hip/hip_runtime.h>

// VQ-VAE vector quantization, MI355X gfx950.
// B=16, C=64, H=W=64 -> N=65536 pixels; K=1024 codes, dim 64.
// NUMERICS (DO NOT CHANGE — r7 passed absmax 0.0 with exactly this):
//   nz/ne: numpy pairwise sum, 8-accumulator unroll, products rounded
//          separately (no fma contraction);
//   dot:   single ascending fp32 fma chain per (pixel,code);
//   d = fl( fl(nz - fl(2*dot)) + ne ); strict-< ascending-k tie-break.
//   ~135 pixels are decided by quantized ties.
//
// Perf history:
//   r7  PXT=1 LDS-broadcast                 161 µs
//   r8  uniform vector global loads         185 µs (vector-L1 path worse)
//   r9  PXT=2 @ (256,2)                     137 µs argmin (VALUBusy 65%, occ 20%)
//   r12 PXT=4 @ (256,1)                     242 µs argmin — VALUBusy 38.7%,
//       VALU-busy TIME flat (~90 µs): latency hiding comes from TLP, not ILP.
//       1 wave/SIMD idles on lgkmcnt; 256-float zr spilled (FETCH +7MB).
//       Fused prep + fused loss both bit-validated (absmax 0.0) — kept.
// r13: PXT=2 @ __launch_bounds__(256,3): 3 blocks/CU, 12 waves/CU,
//      ~170 reg/wave budget (zr=128 in AGPR + thin prefetch). Tests the
//      revised theory that r9's 35% idle is latency-hiding shortfall.
//      Known accepted cost: sn compute from LDS is 32-way conflicted (~2M
//      cycles total, ~2-4 µs) — numerics-exact, fix later if it matters.
#define N_PIX   65536
#define CDIM    64
#define KCODES  1024
#define HWSZ    4096          // H*W
#define KCHUNK  128           // codes per argmin block
#define NCHUNK  8             // KCODES / KCHUNK
#define TPB     256
#define PXT     2             // pixels per thread; 128*256*2 == N_PIX exactly
#define GRIDX   (N_PIX / (TPB * PXT))   // 128

// workspace layout (float-element offsets)
#define OFF_CTR  0            // 1 u32: finalize done-counter
#define OFF_MIN  1024         // 65536*8 f32: per-chunk min score
#define OFF_IDX  525312       // 65536*8 i32: per-chunk argmin
#define OFF_LOSS 1049600      // 1 f32: SSE accumulator

// output layout (float-element offsets): z_q | indices | loss
#define OUT_IDX  (N_PIX * CDIM)         // 4194304
#define OUT_LOSS (OUT_IDX + N_PIX)      // 4259840

// exact numpy pairwise ||.||^2 for pixel registers — EXACT r9-verified form.
__device__ __forceinline__ float np_nz(const float* zr) {
    float r0 = zr[0]*zr[0], r1 = zr[1]*zr[1], r2 = zr[2]*zr[2], r3 = zr[3]*zr[3];
    float r4 = zr[4]*zr[4], r5 = zr[5]*zr[5], r6 = zr[6]*zr[6], r7 = zr[7]*zr[7];
#pragma unroll
    for (int i = 8; i < CDIM; i += 8) {
        r0 = r0 + zr[i+0]*zr[i+0]; r1 = r1 + zr[i+1]*zr[i+1];
        r2 = r2 + zr[i+2]*zr[i+2]; r3 = r3 + zr[i+3]*zr[i+3];
        r4 = r4 + zr[i+4]*zr[i+4]; r5 = r5 + zr[i+5]*zr[i+5];
        r6 = r6 + zr[i+6]*zr[i+6]; r7 = r7 + zr[i+7]*zr[i+7];
    }
    return ((r0 + r1) + (r2 + r3)) + ((r4 + r5) + (r6 + r7));
}

// ---------------- Kernel A: split-K argmin, 2 px/thread, LDS broadcast ------
// grid = (GRIDX, NCHUNK); block = TPB. Also computes ||e||^2 per chunk
// (fused prep, r12-validated) and zeroes the loss slot + done counter.
__global__ __launch_bounds__(TPB, 3) void vq_argmin(const float* __restrict__ z,
                                                    const float* __restrict__ emb,
                                                    float* __restrict__ cmin,
                                                    int* __restrict__ cidx,
                                                    float* __restrict__ ws) {
#pragma clang fp contract(off)
    __shared__ float se[KCHUNK * CDIM];   // 32 KB
    __shared__ float sn[KCHUNK];

    const int chunk = blockIdx.y;
    const int k0 = chunk * KCHUNK;

    if ((blockIdx.x | blockIdx.y) == 0 && threadIdx.x == 0) {
        ws[OFF_LOSS] = 0.0f;                       // stream-ordered before finalize
        ((unsigned*)ws)[OFF_CTR] = 0u;             // graph-replay / re-poison safe
    }

    // stage this chunk's embedding rows (coalesced float4)
    const float4* esrc = (const float4*)(emb + (size_t)k0 * CDIM);
    float4* edst = (float4*)se;
    for (int i = threadIdx.x; i < KCHUNK * CDIM / 4; i += TPB) edst[i] = esrc[i];
    __syncthreads();
    // fused prep: ||e_k||^2 from the bit-exact staged copy (r12-validated).
    if (threadIdx.x < KCHUNK) {
        const float* e = se + threadIdx.x * CDIM;
        float r0 = e[0]*e[0], r1 = e[1]*e[1], r2 = e[2]*e[2], r3 = e[3]*e[3];
        float r4 = e[4]*e[4], r5 = e[5]*e[5], r6 = e[6]*e[6], r7 = e[7]*e[7];
#pragma unroll
        for (int i = 8; i < CDIM; i += 8) {
            r0 = r0 + e[i+0]*e[i+0]; r1 = r1 + e[i+1]*e[i+1];
            r2 = r2 + e[i+2]*e[i+2]; r3 = r3 + e[i+3]*e[i+3];
            r4 = r4 + e[i+4]*e[i+4]; r5 = r5 + e[i+5]*e[i+5];
            r6 = r6 + e[i+6]*e[i+6]; r7 = r7 + e[i+7]*e[i+7];
        }
        sn[threadIdx.x] = ((r0 + r1) + (r2 + r3)) + ((r4 + r5) + (r6 + r7));
    }
    __syncthreads();

    // two pixels per thread, lane-coalesced; no tail (128*256*2 == N_PIX)
    const int p0 = blockIdx.x * (TPB * PXT) + threadIdx.x;
    const int p1 = p0 + TPB;

    float zr0[CDIM], zr1[CDIM];
    {
        const int b0  = p0 >> 12, hw0 = p0 & (HWSZ - 1);
        const int b1  = p1 >> 12, hw1 = p1 & (HWSZ - 1);
        const float* zp0 = z + ((size_t)(b0 * CDIM) << 12) + hw0;
        const float* zp1 = z + ((size_t)(b1 * CDIM) << 12) + hw1;
#pragma unroll
        for (int c = 0; c < CDIM; ++c) {
            zr0[c] = zp0[(size_t)c << 12];
            zr1[c] = zp1[(size_t)c << 12];
        }
    }
    const float nz0 = np_nz(zr0);
    const float nz1 = np_nz(zr1);

    float best0 = 3.4e38f, best1 = 3.4e38f;
    int   bi0   = k0,      bi1   = k0;
    for (int kk = 0; kk < KCHUNK; kk += 2) {
        const float4* e0 = (const float4*)(se + kk * CDIM);
        const float4* e1 = e0 + (CDIM / 4);
        float a00 = 0.f, a01 = 0.f, a10 = 0.f, a11 = 0.f;
#pragma unroll
        for (int j = 0; j < 16; ++j) {
            float4 v0 = e0[j];                 // uniform addr -> LDS broadcast
            float4 v1 = e1[j];
            a00 = fmaf(zr0[4*j+0], v0.x, a00);
            a00 = fmaf(zr0[4*j+1], v0.y, a00);
            a00 = fmaf(zr0[4*j+2], v0.z, a00);
            a00 = fmaf(zr0[4*j+3], v0.w, a00);
            a01 = fmaf(zr0[4*j+0], v1.x, a01);
            a01 = fmaf(zr0[4*j+1], v1.y, a01);
            a01 = fmaf(zr0[4*j+2], v1.z, a01);
            a01 = fmaf(zr0[4*j+3], v1.w, a01);
            a10 = fmaf(zr1[4*j+0], v0.x, a10);
            a10 = fmaf(zr1[4*j+1], v0.y, a10);
            a10 = fmaf(zr1[4*j+2], v0.z, a10);
            a10 = fmaf(zr1[4*j+3], v0.w, a10);
            a11 = fmaf(zr1[4*j+0], v1.x, a11);
            a11 = fmaf(zr1[4*j+1], v1.y, a11);
            a11 = fmaf(zr1[4*j+2], v1.z, a11);
            a11 = fmaf(zr1[4*j+3], v1.w, a11);
        }
        float d00 = (nz0 - 2.0f * a00) + sn[kk];
        float d01 = (nz0 - 2.0f * a01) + sn[kk + 1];
        float d10 = (nz1 - 2.0f * a10) + sn[kk];
        float d11 = (nz1 - 2.0f * a11) + sn[kk + 1];
        if (d00 < best0) { best0 = d00; bi0 = k0 + kk; }
        if (d01 < best0) { best0 = d01; bi0 = k0 + kk + 1; }
        if (d10 < best1) { best1 = d10; bi1 = k0 + kk; }
        if (d11 < best1) { best1 = d11; bi1 = k0 + kk + 1; }
    }
    cmin[(p0 << 3) + chunk] = best0;
    cidx[(p0 << 3) + chunk] = bi0;
    cmin[(p1 << 3) + chunk] = best1;
    cidx[(p1 << 3) + chunk] = bi1;
}

// ---------------- Kernel B: reduce chunks, gather z_q, loss + emit ----------
__global__ __launch_bounds__(TPB) void vq_finalize(const float* __restrict__ z,
                                                   const float* __restrict__ emb,
                                                   const float* __restrict__ cmin,
                                                   const int* __restrict__ cidx,
                                                   float* __restrict__ out,
                                                   float* __restrict__ ws) {
    const int p = blockIdx.x * TPB + threadIdx.x;

    // ascending-chunk strict < keeps the earliest (lowest-k) minimum
    float best = cmin[p << 3];
    int   bi   = cidx[p << 3];
#pragma unroll
    for (int ch = 1; ch < NCHUNK; ++ch) {
        float m = cmin[(p << 3) + ch];
        if (m < best) { best = m; bi = cidx[(p << 3) + ch]; }
    }

    out[OUT_IDX + p] = (float)bi;       // indices output (fp32)

    const float* ev = emb + bi * CDIM;
    const int b  = p >> 12;
    const int hw = p & (HWSZ - 1);
    const float* zp = z + ((size_t)(b * CDIM) << 12) + hw;
    float* zq = out + ((size_t)(b * CDIM) << 12) + hw;

    float ls = 0.0f;
#pragma unroll
    for (int c = 0; c < CDIM; ++c) {
        float e = ev[c];                    // gather: rows hit L1/L2 (256KB table)
        float zv = zp[(size_t)c << 12];
        float d = e - zv;
        ls = fmaf(d, d, ls);
        zq[(size_t)c << 12] = e;            // fp32 z_q, coalesced strided store
    }

    // block reduction -> one atomic per block; last block scales + emits loss
#pragma unroll
    for (int off = 32; off > 0; off >>= 1) ls += __shfl_down(ls, off);
    __shared__ float wsum[TPB / 64];
    if ((threadIdx.x & 63) == 0) wsum[threadIdx.x >> 6] = ls;
    __syncthreads();
    if (threadIdx.x == 0) {
        float s = wsum[0] + wsum[1] + wsum[2] + wsum[3];
        float* loss_acc = ws + OFF_LOSS;
        atomicAdd(loss_acc, s);
        __threadfence();                               // add visible before count
        unsigned* ctr = (unsigned*)ws + OFF_CTR;
        unsigned old = atomicAdd(ctr, 1u);
        if (old == (unsigned)(gridDim.x - 1)) {        // last block: all adds done
            __threadfence();
            float total = atomicAdd(loss_acc, 0.0f);   // coherent L2 read
            // vq_loss + beta*commitment = (1+0.25) * SSE / numel(z)
            out[OUT_LOSS] = total * (1.25f / (float)(N_PIX * CDIM));
        }
    }
}

extern "C" void kernel_launch(void* const* d_in, const int* in_sizes, int n_in,
                              void* d_out, int out_size, void* d_ws, size_t ws_size,
                              hipStream_t stream) {
    const float* z   = (const float*)d_in[0];
    const float* emb = (const float*)d_in[1];
    float* ws   = (float*)d_ws;
    float* out  = (float*)d_out;
    float* cmin = ws + OFF_MIN;
    int*   cidx = (int*)(ws + OFF_IDX);

    vq_argmin<<<dim3(GRIDX, NCHUNK), dim3(TPB), 0, stream>>>(z, emb, cmin, cidx, ws);
    vq_finalize<<<dim3(N_PIX / TPB), dim3(TPB), 0, stream>>>(z, emb, cmin, cidx, out, ws);
}